// Round 1
// baseline (946.325 us; speedup 1.0000x reference)
//
#include <hip/hip_runtime.h>

#define NN 100000
#define NE 1600000
#define HID 64
#define NL 3
#define BN_EPS 1e-5f
#define SCAN_B 1024

// ---------------- CSR build ----------------
__global__ void k_hist(const int* __restrict__ dst, int* __restrict__ counts) {
    int e = blockIdx.x * blockDim.x + threadIdx.x;
    if (e < NE) atomicAdd(&counts[dst[e]], 1);
}

__global__ void k_scan1(const int* __restrict__ counts, int* __restrict__ offs,
                        int* __restrict__ bsum) {
    __shared__ int tmp[SCAN_B];
    int tid = threadIdx.x;
    int gid = blockIdx.x * SCAN_B + tid;
    int v = (gid < NN) ? counts[gid] : 0;
    tmp[tid] = v;
    __syncthreads();
    for (int d = 1; d < SCAN_B; d <<= 1) {
        int t = (tid >= d) ? tmp[tid - d] : 0;
        __syncthreads();
        tmp[tid] += t;
        __syncthreads();
    }
    if (gid < NN) offs[gid] = tmp[tid] - v;   // exclusive within block
    if (tid == SCAN_B - 1) bsum[blockIdx.x] = tmp[tid];
}

__global__ void k_scan2(int* __restrict__ bsum, int nb) {
    if (threadIdx.x == 0) {
        int run = 0;
        for (int i = 0; i < nb; ++i) { int t = bsum[i]; bsum[i] = run; run += t; }
    }
}

__global__ void k_scan3(int* __restrict__ offs, const int* __restrict__ bsum,
                        int* __restrict__ cursor) {
    int gid = blockIdx.x * SCAN_B + threadIdx.x;
    if (gid < NN) {
        int v = offs[gid] + bsum[blockIdx.x];
        offs[gid] = v;
        cursor[gid] = v;
    }
    if (gid == 0) offs[NN] = NE;
}

__global__ void k_scatter(const int* __restrict__ ei, const float* __restrict__ att,
                          int* __restrict__ cursor, int* __restrict__ ssrc,
                          float* __restrict__ satt) {
    int e = blockIdx.x * blockDim.x + threadIdx.x;
    if (e >= NE) return;
    int d = ei[NE + e];
    int p = atomicAdd(&cursor[d], 1);
    ssrc[p] = ei[e];
    satt[p] = att[e];
}

// ---------------- aggregation: one wave per node ----------------
__global__ __launch_bounds__(256) void k_agg(const float* __restrict__ x,
                                             const int* __restrict__ offs,
                                             const int* __restrict__ ssrc,
                                             const float* __restrict__ satt,
                                             float* __restrict__ out) {
    int node = blockIdx.x * 4 + (threadIdx.x >> 6);
    int c = threadIdx.x & 63;
    if (node >= NN) return;
    float acc = x[node * HID + c];            // fold the +x (eps=0) here
    int e0 = offs[node], e1 = offs[node + 1];
    for (int e = e0; e < e1; ++e) {
        int s = ssrc[e];
        float a = satt[e];
        acc += x[s * HID + c] * a;
    }
    out[node * HID + c] = acc;
}

// ---------------- MLP part 1: h = h @ W1 + b1, accumulate BN stats ----------------
__global__ __launch_bounds__(256) void k_mlp1(const float* __restrict__ W1,
                                              const float* __restrict__ b1,
                                              float* __restrict__ h,
                                              float* __restrict__ stats) {
    __shared__ float Wl[HID * HID];
    __shared__ float bl[HID];
    __shared__ float rows[4][HID];
    __shared__ float red[8][HID];
    int tid = threadIdx.x;
    for (int i = tid; i < HID * HID; i += 256) Wl[i] = W1[i];
    if (tid < HID) bl[tid] = b1[tid];
    int r = tid >> 6, c = tid & 63;
    float s1 = 0.f, s2 = 0.f;
    __syncthreads();
    for (int base = blockIdx.x * 4; base < NN; base += gridDim.x * 4) {
        rows[r][c] = h[(base + r) * HID + c];
        __syncthreads();
        float acc = bl[c];
#pragma unroll
        for (int k = 0; k < HID; ++k) acc += rows[r][k] * Wl[k * HID + c];
        h[(base + r) * HID + c] = acc;   // in-place: row already staged in LDS
        s1 += acc;
        s2 += acc * acc;
        __syncthreads();
    }
    red[r][c] = s1;
    red[4 + r][c] = s2;
    __syncthreads();
    if (r == 0) {
        float t1 = red[0][c] + red[1][c] + red[2][c] + red[3][c];
        float t2 = red[4][c] + red[5][c] + red[6][c] + red[7][c];
        atomicAdd(&stats[c], t1);
        atomicAdd(&stats[HID + c], t2);
    }
}

// ---------------- MLP part 2: BN -> ReLU -> @W2+b2 -> ReLU ----------------
__global__ __launch_bounds__(256) void k_mlp2(const float* __restrict__ W2,
                                              const float* __restrict__ b2,
                                              const float* __restrict__ gamma,
                                              const float* __restrict__ beta,
                                              const float* __restrict__ stats,
                                              const float* __restrict__ h,
                                              float* __restrict__ out) {
    __shared__ float Wl[HID * HID];
    __shared__ float bl[HID];
    __shared__ float aC[HID], bC[HID];
    __shared__ float rows[4][HID];
    int tid = threadIdx.x;
    for (int i = tid; i < HID * HID; i += 256) Wl[i] = W2[i];
    if (tid < HID) {
        bl[tid] = b2[tid];
        float mu = stats[tid] * (1.0f / NN);
        float var = stats[HID + tid] * (1.0f / NN) - mu * mu;
        var = fmaxf(var, 0.f);
        float a = gamma[tid] * rsqrtf(var + BN_EPS);
        aC[tid] = a;
        bC[tid] = beta[tid] - mu * a;
    }
    int r = tid >> 6, c = tid & 63;
    __syncthreads();
    for (int base = blockIdx.x * 4; base < NN; base += gridDim.x * 4) {
        float v = h[(base + r) * HID + c];
        v = fmaxf(aC[c] * v + bC[c], 0.f);   // BN + ReLU
        rows[r][c] = v;
        __syncthreads();
        float acc = bl[c];
#pragma unroll
        for (int k = 0; k < HID; ++k) acc += rows[r][k] * Wl[k * HID + c];
        out[(base + r) * HID + c] = fmaxf(acc, 0.f);
        __syncthreads();
    }
}

extern "C" void kernel_launch(void* const* d_in, const int* in_sizes, int n_in,
                              void* d_out, int out_size, void* d_ws, size_t ws_size,
                              hipStream_t stream) {
    const float* x_in  = (const float*)d_in[0];
    const int*   ei    = (const int*)d_in[1];
    const float* att   = (const float*)d_in[2];
    const float* W1    = (const float*)d_in[3];
    const float* b1    = (const float*)d_in[4];
    const float* gamma = (const float*)d_in[5];
    const float* beta  = (const float*)d_in[6];
    const float* W2    = (const float*)d_in[7];
    const float* b2    = (const float*)d_in[8];
    float* out = (float*)d_out;

    char* ws = (char*)d_ws;
    size_t off = 0;
    auto alloc = [&](size_t bytes) -> void* {
        void* p = ws + off;
        off += (bytes + 255) & ~(size_t)255;
        return p;
    };
    float* hbuf   = (float*)alloc((size_t)NN * HID * 4);
    float* xbuf   = (float*)alloc((size_t)NN * HID * 4);
    int*   counts = (int*)alloc((size_t)NN * 4);
    int*   offs   = (int*)alloc((size_t)(NN + 1) * 4);
    int*   cursor = (int*)alloc((size_t)NN * 4);
    int*   ssrc   = (int*)alloc((size_t)NE * 4);
    float* satt   = (float*)alloc((size_t)NE * 4);
    int*   bsum   = (int*)alloc(4096);
    float* stats  = (float*)alloc(NL * 128 * 4);

    hipMemsetAsync(counts, 0, (size_t)NN * 4, stream);
    hipMemsetAsync(stats, 0, NL * 128 * 4, stream);

    int nb = (NN + SCAN_B - 1) / SCAN_B;
    k_hist<<<(NE + 255) / 256, 256, 0, stream>>>(ei + NE, counts);
    k_scan1<<<nb, SCAN_B, 0, stream>>>(counts, offs, bsum);
    k_scan2<<<1, 64, 0, stream>>>(bsum, nb);
    k_scan3<<<nb, SCAN_B, 0, stream>>>(offs, bsum, cursor);
    k_scatter<<<(NE + 255) / 256, 256, 0, stream>>>(ei, att, cursor, ssrc, satt);

    const float* xcur = x_in;
    float* targets[NL] = {xbuf, out, out};
    for (int l = 0; l < NL; ++l) {
        k_agg<<<NN / 4, 256, 0, stream>>>(xcur, offs, ssrc, satt, hbuf);
        k_mlp1<<<1024, 256, 0, stream>>>(W1 + (size_t)l * HID * HID, b1 + l * HID,
                                         hbuf, stats + l * 128);
        k_mlp2<<<1024, 256, 0, stream>>>(W2 + (size_t)l * HID * HID, b2 + l * HID,
                                         gamma + l * HID, beta + l * HID,
                                         stats + l * 128, hbuf, targets[l]);
        xcur = targets[l];
    }
}

// Round 2
// 681.801 us; speedup vs baseline: 1.3880x; 1.3880x over previous
//
#include <hip/hip_runtime.h>

#define NN 100000
#define NE 1600000
#define HID 64
#define NL 3
#define BN_EPS 1e-5f
#define SCAN_B 1024

// ---------------- CSR build ----------------
__global__ void k_hist(const int* __restrict__ dst, int* __restrict__ counts) {
    int e = blockIdx.x * blockDim.x + threadIdx.x;
    if (e < NE) atomicAdd(&counts[dst[e]], 1);
}

__global__ void k_scan1(const int* __restrict__ counts, int* __restrict__ offs,
                        int* __restrict__ bsum) {
    __shared__ int tmp[SCAN_B];
    int tid = threadIdx.x;
    int gid = blockIdx.x * SCAN_B + tid;
    int v = (gid < NN) ? counts[gid] : 0;
    tmp[tid] = v;
    __syncthreads();
    for (int d = 1; d < SCAN_B; d <<= 1) {
        int t = (tid >= d) ? tmp[tid - d] : 0;
        __syncthreads();
        tmp[tid] += t;
        __syncthreads();
    }
    if (gid < NN) offs[gid] = tmp[tid] - v;   // exclusive within block
    if (tid == SCAN_B - 1) bsum[blockIdx.x] = tmp[tid];
}

// parallel exclusive scan of block sums (nb <= 128)
__global__ void k_scan2(int* __restrict__ bsum, int nb) {
    __shared__ int t[128];
    int tid = threadIdx.x;
    int v = (tid < nb) ? bsum[tid] : 0;
    t[tid] = v;
    __syncthreads();
    for (int d = 1; d < 128; d <<= 1) {
        int u = (tid >= d) ? t[tid - d] : 0;
        __syncthreads();
        t[tid] += u;
        __syncthreads();
    }
    if (tid < nb) bsum[tid] = t[tid] - v;
}

__global__ void k_scan3(int* __restrict__ offs, const int* __restrict__ bsum,
                        int* __restrict__ cursor) {
    int gid = blockIdx.x * SCAN_B + threadIdx.x;
    if (gid < NN) {
        int v = offs[gid] + bsum[blockIdx.x];
        offs[gid] = v;
        cursor[gid] = v;
    }
    if (gid == 0) offs[NN] = NE;
}

__global__ void k_scatter(const int* __restrict__ ei, const float* __restrict__ att,
                          int* __restrict__ cursor, int2* __restrict__ ev) {
    int e = blockIdx.x * blockDim.x + threadIdx.x;
    if (e >= NE) return;
    int s = ei[e];
    int d = ei[NE + e];
    float a = att[e];
    int p = atomicAdd(&cursor[d], 1);
    ev[p] = make_int2(s, __float_as_int(a));
}

// ------- kernel A: agg (gather+scale+sum, +x) -> Linear1 -> BN-stats -------
__global__ __launch_bounds__(256) void k_layerA(const float* __restrict__ x,
                                                const int* __restrict__ offs,
                                                const int2* __restrict__ ev,
                                                const float* __restrict__ W1,
                                                const float* __restrict__ b1,
                                                float* __restrict__ h,
                                                float* __restrict__ stats) {
    __shared__ float rowlds[4][HID];
    __shared__ float red[8][HID];
    int tid = threadIdx.x;
    int wv = tid >> 6, c = tid & 63;
    float wr[HID];
#pragma unroll
    for (int k = 0; k < HID; ++k) wr[k] = W1[k * HID + c];   // W column c in regs
    float bl = b1[c];
    float s1 = 0.f, s2 = 0.f;
    int gw = blockIdx.x * 4 + wv;
    int nw = gridDim.x * 4;
    for (int node = gw; node < NN; node += nw) {
        float acc = x[(size_t)node * HID + c];               // +x (eps=0)
        int e = offs[node], e1 = offs[node + 1];
        for (; e + 4 <= e1; e += 4) {                        // 4 rows in flight
            int2 v0 = ev[e], v1 = ev[e + 1], v2 = ev[e + 2], v3 = ev[e + 3];
            float r0 = x[(size_t)v0.x * HID + c];
            float r1 = x[(size_t)v1.x * HID + c];
            float r2 = x[(size_t)v2.x * HID + c];
            float r3 = x[(size_t)v3.x * HID + c];
            acc += r0 * __int_as_float(v0.y) + r1 * __int_as_float(v1.y)
                 + r2 * __int_as_float(v2.y) + r3 * __int_as_float(v3.y);
        }
        for (; e < e1; ++e) {
            int2 v = ev[e];
            acc += x[(size_t)v.x * HID + c] * __int_as_float(v.y);
        }
        // wave-synchronous row exchange (no barrier: per-wave buffer)
        rowlds[wv][c] = acc;
        float o = bl;
        const float4* rp = (const float4*)&rowlds[wv][0];
#pragma unroll
        for (int k4 = 0; k4 < 16; ++k4) {
            float4 rv = rp[k4];
            o += rv.x * wr[4 * k4 + 0] + rv.y * wr[4 * k4 + 1]
               + rv.z * wr[4 * k4 + 2] + rv.w * wr[4 * k4 + 3];
        }
        h[(size_t)node * HID + c] = o;
        s1 += o;
        s2 += o * o;
    }
    red[wv][c] = s1;
    red[4 + wv][c] = s2;
    __syncthreads();
    if (wv == 0) {
        atomicAdd(&stats[c], red[0][c] + red[1][c] + red[2][c] + red[3][c]);
        atomicAdd(&stats[HID + c], red[4][c] + red[5][c] + red[6][c] + red[7][c]);
    }
}

// ------- kernel B: BN -> ReLU -> Linear2 -> ReLU -------
__global__ __launch_bounds__(256) void k_layerB(const float* __restrict__ W2,
                                                const float* __restrict__ b2,
                                                const float* __restrict__ gamma,
                                                const float* __restrict__ beta,
                                                const float* __restrict__ stats,
                                                const float* __restrict__ h,
                                                float* __restrict__ out) {
    __shared__ float rowlds[4][HID];
    int tid = threadIdx.x;
    int wv = tid >> 6, c = tid & 63;
    float wr[HID];
#pragma unroll
    for (int k = 0; k < HID; ++k) wr[k] = W2[k * HID + c];
    float bl = b2[c];
    float mu = stats[c] * (1.0f / NN);
    float var = fmaxf(stats[HID + c] * (1.0f / NN) - mu * mu, 0.f);
    float aC = gamma[c] * rsqrtf(var + BN_EPS);
    float bC = beta[c] - mu * aC;
    int gw = blockIdx.x * 4 + wv;
    int nw = gridDim.x * 4;
    for (int node = gw; node < NN; node += nw) {
        float v = h[(size_t)node * HID + c];
        v = fmaxf(aC * v + bC, 0.f);                          // BN + ReLU
        rowlds[wv][c] = v;
        float o = bl;
        const float4* rp = (const float4*)&rowlds[wv][0];
#pragma unroll
        for (int k4 = 0; k4 < 16; ++k4) {
            float4 rv = rp[k4];
            o += rv.x * wr[4 * k4 + 0] + rv.y * wr[4 * k4 + 1]
               + rv.z * wr[4 * k4 + 2] + rv.w * wr[4 * k4 + 3];
        }
        out[(size_t)node * HID + c] = fmaxf(o, 0.f);
    }
}

extern "C" void kernel_launch(void* const* d_in, const int* in_sizes, int n_in,
                              void* d_out, int out_size, void* d_ws, size_t ws_size,
                              hipStream_t stream) {
    const float* x_in  = (const float*)d_in[0];
    const int*   ei    = (const int*)d_in[1];
    const float* att   = (const float*)d_in[2];
    const float* W1    = (const float*)d_in[3];
    const float* b1    = (const float*)d_in[4];
    const float* gamma = (const float*)d_in[5];
    const float* beta  = (const float*)d_in[6];
    const float* W2    = (const float*)d_in[7];
    const float* b2    = (const float*)d_in[8];
    float* out = (float*)d_out;

    char* ws = (char*)d_ws;
    size_t off = 0;
    auto alloc = [&](size_t bytes) -> void* {
        void* p = ws + off;
        off += (bytes + 255) & ~(size_t)255;
        return p;
    };
    float* hbuf   = (float*)alloc((size_t)NN * HID * 4);
    float* xbuf   = (float*)alloc((size_t)NN * HID * 4);
    int*   counts = (int*)alloc((size_t)NN * 4);
    int*   offs   = (int*)alloc((size_t)(NN + 1) * 4);
    int*   cursor = (int*)alloc((size_t)NN * 4);
    int2*  ev     = (int2*)alloc((size_t)NE * 8);
    int*   bsum   = (int*)alloc(4096);
    float* stats  = (float*)alloc(NL * 128 * 4);

    hipMemsetAsync(counts, 0, (size_t)NN * 4, stream);
    hipMemsetAsync(stats, 0, NL * 128 * 4, stream);

    int nb = (NN + SCAN_B - 1) / SCAN_B;
    k_hist<<<(NE + 255) / 256, 256, 0, stream>>>(ei + NE, counts);
    k_scan1<<<nb, SCAN_B, 0, stream>>>(counts, offs, bsum);
    k_scan2<<<1, 128, 0, stream>>>(bsum, nb);
    k_scan3<<<nb, SCAN_B, 0, stream>>>(offs, bsum, cursor);
    k_scatter<<<(NE + 255) / 256, 256, 0, stream>>>(ei, att, cursor, ev);

    const float* xcur = x_in;
    float* targets[NL] = {xbuf, out, out};
    for (int l = 0; l < NL; ++l) {
        k_layerA<<<2048, 256, 0, stream>>>(xcur, offs, ev,
                                           W1 + (size_t)l * HID * HID, b1 + l * HID,
                                           hbuf, stats + l * 128);
        k_layerB<<<2048, 256, 0, stream>>>(W2 + (size_t)l * HID * HID, b2 + l * HID,
                                           gamma + l * HID, beta + l * HID,
                                           stats + l * 128, hbuf, targets[l]);
        xcur = targets[l];
    }
}

// Round 3
// 636.187 us; speedup vs baseline: 1.4875x; 1.0717x over previous
//
#include <hip/hip_runtime.h>

#define NN 100000
#define NE 1600000
#define HID 64
#define NL 3
#define BN_EPS 1e-5f
#define SCAN_B 1024

__device__ __forceinline__ float bf2f(unsigned short u) {
    union { unsigned int i; float f; } v; v.i = ((unsigned int)u) << 16; return v.f;
}
__device__ __forceinline__ unsigned short f2bf(float f) {
    union { float f; unsigned int i; } v; v.f = f;
    unsigned int r = v.i + 0x7FFFu + ((v.i >> 16) & 1u);   // RNE
    return (unsigned short)(r >> 16);
}

// ---------------- input convert x f32 -> bf16 ----------------
__global__ void k_conv(const float* __restrict__ x, ushort* __restrict__ xb) {
    int i = blockIdx.x * blockDim.x + threadIdx.x;   // over NN*HID/4
    float4 v = ((const float4*)x)[i];
    ushort4 o;
    o.x = f2bf(v.x); o.y = f2bf(v.y); o.z = f2bf(v.z); o.w = f2bf(v.w);
    ((ushort4*)xb)[i] = o;
}

// ---------------- CSR build ----------------
__global__ void k_hist(const int* __restrict__ dst, int* __restrict__ counts) {
    int e = blockIdx.x * blockDim.x + threadIdx.x;
    if (e < NE) atomicAdd(&counts[dst[e]], 1);
}

__global__ void k_scan1(const int* __restrict__ counts, int* __restrict__ offs,
                        int* __restrict__ bsum) {
    __shared__ int tmp[SCAN_B];
    int tid = threadIdx.x;
    int gid = blockIdx.x * SCAN_B + tid;
    int v = (gid < NN) ? counts[gid] : 0;
    tmp[tid] = v;
    __syncthreads();
    for (int d = 1; d < SCAN_B; d <<= 1) {
        int t = (tid >= d) ? tmp[tid - d] : 0;
        __syncthreads();
        tmp[tid] += t;
        __syncthreads();
    }
    if (gid < NN) offs[gid] = tmp[tid] - v;
    if (tid == SCAN_B - 1) bsum[blockIdx.x] = tmp[tid];
}

__global__ void k_scan2(int* __restrict__ bsum, int nb) {
    __shared__ int t[128];
    int tid = threadIdx.x;
    int v = (tid < nb) ? bsum[tid] : 0;
    t[tid] = v;
    __syncthreads();
    for (int d = 1; d < 128; d <<= 1) {
        int u = (tid >= d) ? t[tid - d] : 0;
        __syncthreads();
        t[tid] += u;
        __syncthreads();
    }
    if (tid < nb) bsum[tid] = t[tid] - v;
}

__global__ void k_scan3(int* __restrict__ offs, const int* __restrict__ bsum,
                        int* __restrict__ cursor) {
    int gid = blockIdx.x * SCAN_B + threadIdx.x;
    if (gid < NN) {
        int v = offs[gid] + bsum[blockIdx.x];
        offs[gid] = v;
        cursor[gid] = v;
    }
    if (gid == 0) offs[NN] = NE;
}

__global__ void k_scatter(const int* __restrict__ ei, const float* __restrict__ att,
                          int* __restrict__ cursor, int2* __restrict__ ev) {
    int e = blockIdx.x * blockDim.x + threadIdx.x;
    if (e >= NE) return;
    int s = ei[e];
    int d = ei[NE + e];
    float a = att[e];
    int p = atomicAdd(&cursor[d], 1);
    ev[p] = make_int2(s, __float_as_int(a));
}

// ------- gather: agg = x + sum_{j->i} x_j * a, bf16 rows, scalarized idx -------
__global__ __launch_bounds__(256, 8) void k_gather(const ushort* __restrict__ xb,
                                                   const int* __restrict__ offs,
                                                   const int2* __restrict__ ev,
                                                   ushort* __restrict__ agg) {
    int wv = threadIdx.x >> 6, c = threadIdx.x & 63;
    int node = blockIdx.x * 4 + wv;                 // NN % 4 == 0
    float acc = bf2f(xb[(size_t)node * HID + c]);   // self term (eps=0)
    int e0 = offs[node], e1 = offs[node + 1];
    for (int e = e0; e < e1; e += 8) {
        int idx[8]; float av[8], r[8];
#pragma unroll
        for (int j = 0; j < 8; ++j) {
            int ee = e + j;
            int ec = (ee < e1) ? ee : (e1 - 1);     // clamped tail, a=0
            int2 t = ev[ec];
            idx[j] = __builtin_amdgcn_readfirstlane(t.x);
            int ai = __builtin_amdgcn_readfirstlane(t.y);
            av[j] = (ee < e1) ? __int_as_float(ai) : 0.f;
        }
#pragma unroll
        for (int j = 0; j < 8; ++j) r[j] = bf2f(xb[(size_t)idx[j] * HID + c]);
#pragma unroll
        for (int j = 0; j < 8; ++j) acc += r[j] * av[j];
    }
    agg[(size_t)node * HID + c] = f2bf(acc);
}

// ------- mlp1: h = agg @ W1 + b1 (f32 math), BN stats -------
__global__ __launch_bounds__(256, 4) void k_mlp1(const ushort* __restrict__ agg,
                                                 const float* __restrict__ W1,
                                                 const float* __restrict__ b1,
                                                 ushort* __restrict__ h,
                                                 float* __restrict__ stats) {
    __shared__ float rowlds[4][HID];
    __shared__ float red[8][HID];
    int tid = threadIdx.x, wv = tid >> 6, c = tid & 63;
    float wr[HID];
#pragma unroll
    for (int k = 0; k < HID; ++k) wr[k] = W1[k * HID + c];
    float bl = b1[c];
    float s1 = 0.f, s2 = 0.f;
    int gw = blockIdx.x * 4 + wv, nw = gridDim.x * 4;
    for (int node = gw; node < NN; node += nw) {
        rowlds[wv][c] = bf2f(agg[(size_t)node * HID + c]);
        float o = bl;
        const float4* rp = (const float4*)&rowlds[wv][0];
#pragma unroll
        for (int k4 = 0; k4 < 16; ++k4) {
            float4 rv = rp[k4];
            o += rv.x * wr[4 * k4] + rv.y * wr[4 * k4 + 1]
               + rv.z * wr[4 * k4 + 2] + rv.w * wr[4 * k4 + 3];
        }
        h[(size_t)node * HID + c] = f2bf(o);
        s1 += o;
        s2 += o * o;
    }
    red[wv][c] = s1;
    red[4 + wv][c] = s2;
    __syncthreads();
    if (wv == 0) {
        atomicAdd(&stats[c], red[0][c] + red[1][c] + red[2][c] + red[3][c]);
        atomicAdd(&stats[HID + c], red[4][c] + red[5][c] + red[6][c] + red[7][c]);
    }
}

// ------- mlp2: BN -> ReLU -> @W2+b2 -> ReLU; out bf16 (mid) or f32 (last) -------
__global__ __launch_bounds__(256, 4) void k_mlp2(const float* __restrict__ W2,
                                                 const float* __restrict__ b2,
                                                 const float* __restrict__ gamma,
                                                 const float* __restrict__ beta,
                                                 const float* __restrict__ stats,
                                                 const ushort* __restrict__ h,
                                                 ushort* __restrict__ xb_out,
                                                 float* __restrict__ f_out,
                                                 int write_f32) {
    __shared__ float rowlds[4][HID];
    int tid = threadIdx.x, wv = tid >> 6, c = tid & 63;
    float wr[HID];
#pragma unroll
    for (int k = 0; k < HID; ++k) wr[k] = W2[k * HID + c];
    float bl = b2[c];
    float mu = stats[c] * (1.0f / NN);
    float var = fmaxf(stats[HID + c] * (1.0f / NN) - mu * mu, 0.f);
    float aC = gamma[c] * rsqrtf(var + BN_EPS);
    float bC = beta[c] - mu * aC;
    int gw = blockIdx.x * 4 + wv, nw = gridDim.x * 4;
    for (int node = gw; node < NN; node += nw) {
        float v = bf2f(h[(size_t)node * HID + c]);
        v = fmaxf(aC * v + bC, 0.f);
        rowlds[wv][c] = v;
        float o = bl;
        const float4* rp = (const float4*)&rowlds[wv][0];
#pragma unroll
        for (int k4 = 0; k4 < 16; ++k4) {
            float4 rv = rp[k4];
            o += rv.x * wr[4 * k4] + rv.y * wr[4 * k4 + 1]
               + rv.z * wr[4 * k4 + 2] + rv.w * wr[4 * k4 + 3];
        }
        o = fmaxf(o, 0.f);
        if (write_f32) f_out[(size_t)node * HID + c] = o;
        else           xb_out[(size_t)node * HID + c] = f2bf(o);
    }
}

extern "C" void kernel_launch(void* const* d_in, const int* in_sizes, int n_in,
                              void* d_out, int out_size, void* d_ws, size_t ws_size,
                              hipStream_t stream) {
    const float* x_in  = (const float*)d_in[0];
    const int*   ei    = (const int*)d_in[1];
    const float* att   = (const float*)d_in[2];
    const float* W1    = (const float*)d_in[3];
    const float* b1    = (const float*)d_in[4];
    const float* gamma = (const float*)d_in[5];
    const float* beta  = (const float*)d_in[6];
    const float* W2    = (const float*)d_in[7];
    const float* b2    = (const float*)d_in[8];
    float* out = (float*)d_out;

    char* ws = (char*)d_ws;
    size_t off = 0;
    auto alloc = [&](size_t bytes) -> void* {
        void* p = ws + off;
        off += (bytes + 255) & ~(size_t)255;
        return p;
    };
    ushort* xb    = (ushort*)alloc((size_t)NN * HID * 2);
    ushort* aggb  = (ushort*)alloc((size_t)NN * HID * 2);
    ushort* hb    = (ushort*)alloc((size_t)NN * HID * 2);
    int*    counts= (int*)alloc((size_t)NN * 4);
    int*    offs  = (int*)alloc((size_t)(NN + 1) * 4);
    int*    cursor= (int*)alloc((size_t)NN * 4);
    int2*   ev    = (int2*)alloc((size_t)NE * 8);
    int*    bsum  = (int*)alloc(4096);
    float*  stats = (float*)alloc(NL * 128 * 4);

    hipMemsetAsync(counts, 0, (size_t)NN * 4, stream);
    hipMemsetAsync(stats, 0, NL * 128 * 4, stream);

    k_conv<<<(NN * HID / 4 + 255) / 256, 256, 0, stream>>>(x_in, xb);

    int nb = (NN + SCAN_B - 1) / SCAN_B;
    k_hist<<<(NE + 255) / 256, 256, 0, stream>>>(ei + NE, counts);
    k_scan1<<<nb, SCAN_B, 0, stream>>>(counts, offs, bsum);
    k_scan2<<<1, 128, 0, stream>>>(bsum, nb);
    k_scan3<<<nb, SCAN_B, 0, stream>>>(offs, bsum, cursor);
    k_scatter<<<(NE + 255) / 256, 256, 0, stream>>>(ei, att, cursor, ev);

    for (int l = 0; l < NL; ++l) {
        k_gather<<<NN / 4, 256, 0, stream>>>(xb, offs, ev, aggb);
        k_mlp1<<<1024, 256, 0, stream>>>(aggb, W1 + (size_t)l * HID * HID,
                                         b1 + l * HID, hb, stats + l * 128);
        k_mlp2<<<1024, 256, 0, stream>>>(W2 + (size_t)l * HID * HID, b2 + l * HID,
                                         gamma + l * HID, beta + l * HID,
                                         stats + l * 128, hb,
                                         xb, out, (l == NL - 1) ? 1 : 0);
    }
}